// Round 6
// baseline (136.628 us; speedup 1.0000x reference)
//
#include <hip/hip_runtime.h>

// Problem constants (from reference setup_inputs)
#define B 4
#define N 8
#define H 384
#define W 384
#define HW (H * W)
#define PPT 4   // pixels per thread -> float4 loads/stores (16 B/lane)

// out[b*N + i][c][h][w] = sum_j softmax_j(-d2[i][j]/alpha) * ab[j][c]
// d2[i][j] = sum_c (lab[j][c] - lab[i][c])^2  (per pixel)
// d2[i][i] == 0 and d2 >= 0 => softmax max is exactly 0: no max-subtraction,
// exp in (0,1], sum >= 1 (rcp safe).
__global__ __launch_bounds__(64) void wavg_color_temporal_kernel(
    const float* __restrict__ x_lab,   // (B, N, 3, H, W)
    const float* __restrict__ x_ab,    // (B, N, 2, H, W)
    const int*   __restrict__ alpha_p, // scalar (int or float bits)
    float*       __restrict__ out)     // (B*N, 2, H, W)
{
    constexpr int per_b = HW / PPT;            // 36864 thread-groups per batch
    const int tid = blockIdx.x * blockDim.x + threadIdx.x;
    // grid exactly covers B * per_b threads; no bounds check needed.

    // alpha: robust to int32 or float32 encoding of the scalar
    int ai = alpha_p[0];
    float alpha = (ai > 0 && ai < (1 << 23)) ? (float)ai : __int_as_float(ai);
    const float nia = -__builtin_amdgcn_rcpf(alpha);   // -1/alpha

    const int b = tid / per_b;
    const int p = (tid % per_b) * PPT;

    const float* lab_b = x_lab + (size_t)b * N * 3 * HW + p;
    const float* ab_b  = x_ab  + (size_t)b * N * 2 * HW + p;
    float*       out_b = out   + (size_t)b * N * 2 * HW + p;

    // Stage all inputs for this 4-pixel group in registers (all-static
    // indexing after unroll -> stays in VGPRs, no scratch).
    float lab[N][3][PPT];
    float ab[N][2][PPT];
#pragma unroll
    for (int j = 0; j < N; ++j) {
#pragma unroll
        for (int c = 0; c < 3; ++c) {
            float4 v = *reinterpret_cast<const float4*>(lab_b + (size_t)(j * 3 + c) * HW);
            lab[j][c][0] = v.x; lab[j][c][1] = v.y; lab[j][c][2] = v.z; lab[j][c][3] = v.w;
        }
#pragma unroll
        for (int c = 0; c < 2; ++c) {
            float4 v = *reinterpret_cast<const float4*>(ab_b + (size_t)(j * 2 + c) * HW);
            ab[j][c][0] = v.x; ab[j][c][1] = v.y; ab[j][c][2] = v.z; ab[j][c][3] = v.w;
        }
    }

#pragma unroll
    for (int i = 0; i < N; ++i) {
        float s[PPT], a0[PPT], a1[PPT];
#pragma unroll
        for (int q = 0; q < PPT; ++q) { s[q] = 0.f; a0[q] = 0.f; a1[q] = 0.f; }
#pragma unroll
        for (int j = 0; j < N; ++j) {
#pragma unroll
            for (int q = 0; q < PPT; ++q) {
                float d0 = lab[j][0][q] - lab[i][0][q];
                float d1 = lab[j][1][q] - lab[i][1][q];
                float d2 = lab[j][2][q] - lab[i][2][q];
                float dd = d0 * d0 + d1 * d1 + d2 * d2;
                float w  = __expf(dd * nia);
                s[q]  += w;
                a0[q] += w * ab[j][0][q];
                a1[q] += w * ab[j][1][q];
            }
        }
        float4 o0, o1;
        {
            float r0 = __builtin_amdgcn_rcpf(s[0]);
            float r1 = __builtin_amdgcn_rcpf(s[1]);
            float r2 = __builtin_amdgcn_rcpf(s[2]);
            float r3 = __builtin_amdgcn_rcpf(s[3]);
            o0.x = a0[0] * r0; o0.y = a0[1] * r1; o0.z = a0[2] * r2; o0.w = a0[3] * r3;
            o1.x = a1[0] * r0; o1.y = a1[1] * r1; o1.z = a1[2] * r2; o1.w = a1[3] * r3;
        }
        *reinterpret_cast<float4*>(out_b + (size_t)(i * 2 + 0) * HW) = o0;
        *reinterpret_cast<float4*>(out_b + (size_t)(i * 2 + 1) * HW) = o1;
    }
}

extern "C" void kernel_launch(void* const* d_in, const int* in_sizes, int n_in,
                              void* d_out, int out_size, void* d_ws, size_t ws_size,
                              hipStream_t stream) {
    const float* x_lab = (const float*)d_in[0];
    const float* x_ab  = (const float*)d_in[1];
    const int*   alpha = (const int*)d_in[2];
    float* out = (float*)d_out;

    const int total_threads = B * (HW / PPT);  // 4 * 36864 = 147456
    const int block = 64;                      // 1 wave/block
    const int grid = total_threads / block;    // 2304 blocks = exactly 9 waves/CU
    wavg_color_temporal_kernel<<<grid, block, 0, stream>>>(x_lab, x_ab, alpha, out);
}

// Round 10
// 130.726 us; speedup vs baseline: 1.0451x; 1.0451x over previous
//
#include <hip/hip_runtime.h>

// Problem constants (from reference setup_inputs)
#define B 4
#define N 8
#define H 384
#define W 384
#define HW (H * W)
#define PPT 2   // pixels per thread -> float2 loads/stores (8 B/lane)

// out[b*N + i][c][h][w] = sum_j softmax_j(-d2[i][j]/alpha) * ab[j][c]
// d2[i][j] = sum_c (lab[j][c] - lab[i][c])^2  (per pixel)
// d2[i][i] == 0 and d2 >= 0 => softmax max is exactly 0: no max-subtraction,
// exp in (0,1], sum >= 1 (rcp safe).
//
// R6 counters: 43.5us, 24% HBM, VALUBusy 23%, Occ 12% -> latency-bound.
// Fix: PPT 4->2 doubles wave count (2304->4608 = 18 waves/CU) and halves
// per-thread staging (40 float2 = 80 VGPR) so all 40 loads stay in flight.
__global__ __launch_bounds__(64) void wavg_color_temporal_kernel(
    const float* __restrict__ x_lab,   // (B, N, 3, H, W)
    const float* __restrict__ x_ab,    // (B, N, 2, H, W)
    const int*   __restrict__ alpha_p, // scalar (int or float bits)
    float*       __restrict__ out)     // (B*N, 2, H, W)
{
    constexpr int per_b = HW / PPT;            // 73728 threads per batch
    const int tid = blockIdx.x * blockDim.x + threadIdx.x;

    // alpha: robust to int32 or float32 encoding of the scalar
    int ai = alpha_p[0];
    float alpha = (ai > 0 && ai < (1 << 23)) ? (float)ai : __int_as_float(ai);
    // w = exp(-d2/alpha) = exp2(d2 * (-log2e/alpha)) — one mul + v_exp_f32.
    const float nia = -1.4426950408889634f * __builtin_amdgcn_rcpf(alpha);

    const int b = tid / per_b;
    const int p = (tid % per_b) * PPT;

    const float* lab_b = x_lab + (size_t)b * N * 3 * HW + p;
    const float* ab_b  = x_ab  + (size_t)b * N * 2 * HW + p;
    float*       out_b = out   + (size_t)b * N * 2 * HW + p;

    // Stage all inputs for this pixel pair in registers (all-static
    // indexing after unroll -> stays in VGPRs).
    float lab[N][3][PPT];
    float ab[N][2][PPT];
#pragma unroll
    for (int j = 0; j < N; ++j) {
#pragma unroll
        for (int c = 0; c < 3; ++c) {
            float2 v = *reinterpret_cast<const float2*>(lab_b + (size_t)(j * 3 + c) * HW);
            lab[j][c][0] = v.x; lab[j][c][1] = v.y;
        }
#pragma unroll
        for (int c = 0; c < 2; ++c) {
            float2 v = *reinterpret_cast<const float2*>(ab_b + (size_t)(j * 2 + c) * HW);
            ab[j][c][0] = v.x; ab[j][c][1] = v.y;
        }
    }

#pragma unroll
    for (int i = 0; i < N; ++i) {
        float s[PPT], a0[PPT], a1[PPT];
#pragma unroll
        for (int q = 0; q < PPT; ++q) { s[q] = 0.f; a0[q] = 0.f; a1[q] = 0.f; }
#pragma unroll
        for (int j = 0; j < N; ++j) {
#pragma unroll
            for (int q = 0; q < PPT; ++q) {
                float d0 = lab[j][0][q] - lab[i][0][q];
                float d1 = lab[j][1][q] - lab[i][1][q];
                float d2 = lab[j][2][q] - lab[i][2][q];
                float dd = d0 * d0 + d1 * d1 + d2 * d2;
                float w  = __builtin_amdgcn_exp2f(dd * nia);
                s[q]  += w;
                a0[q] += w * ab[j][0][q];
                a1[q] += w * ab[j][1][q];
            }
        }
        float2 o0, o1;
        {
            float r0 = __builtin_amdgcn_rcpf(s[0]);
            float r1 = __builtin_amdgcn_rcpf(s[1]);
            o0.x = a0[0] * r0; o0.y = a0[1] * r1;
            o1.x = a1[0] * r0; o1.y = a1[1] * r1;
        }
        *reinterpret_cast<float2*>(out_b + (size_t)(i * 2 + 0) * HW) = o0;
        *reinterpret_cast<float2*>(out_b + (size_t)(i * 2 + 1) * HW) = o1;
    }
}

extern "C" void kernel_launch(void* const* d_in, const int* in_sizes, int n_in,
                              void* d_out, int out_size, void* d_ws, size_t ws_size,
                              hipStream_t stream) {
    const float* x_lab = (const float*)d_in[0];
    const float* x_ab  = (const float*)d_in[1];
    const int*   alpha = (const int*)d_in[2];
    float* out = (float*)d_out;

    const int total_threads = B * (HW / PPT);  // 4 * 73728 = 294912
    const int block = 64;                      // 1 wave/block
    const int grid = total_threads / block;    // 4608 blocks = exactly 18 waves/CU
    wavg_color_temporal_kernel<<<grid, block, 0, stream>>>(x_lab, x_ab, alpha, out);
}

// Round 15
// 128.812 us; speedup vs baseline: 1.0607x; 1.0149x over previous
//
#include <hip/hip_runtime.h>

// Problem constants (from reference setup_inputs)
#define B 4
#define N 8
#define H 384
#define W 384
#define HW (H * W)

// out[b*N + i][c][h][w] = sum_j softmax_j(-d2[i][j]/alpha) * ab[j][c]
// d2[i][j] = sum_c (lab[j][c] - lab[i][c])^2  (per pixel)
// d2[i][i] == 0 and d2 >= 0 => softmax max is exactly 0: no max-subtraction,
// exp in (0,1], sum >= 1 (rcp safe).
//
// Ladder: R6 PPT=4 (9 w/CU): 43.5us, 24% HBM, Occ 12% -> latency-bound.
//         R10 PPT=2 (18 w/CU): ~37us est.  Trend: TLP is the lever.
// This round PPT=1: 9216 waves (~28-32 resident/CU at ~70 VGPR), scalar
// 4B loads (256B per wave-load, still fully coalesced).
__global__ __launch_bounds__(256) void wavg_color_temporal_kernel(
    const float* __restrict__ x_lab,   // (B, N, 3, H, W)
    const float* __restrict__ x_ab,    // (B, N, 2, H, W)
    const int*   __restrict__ alpha_p, // scalar (int or float bits)
    float*       __restrict__ out)     // (B*N, 2, H, W)
{
    const int tid = blockIdx.x * blockDim.x + threadIdx.x;  // one PIXEL per thread

    // alpha: robust to int32 or float32 encoding of the scalar
    int ai = alpha_p[0];
    float alpha = (ai > 0 && ai < (1 << 23)) ? (float)ai : __int_as_float(ai);
    // w = exp(-d2/alpha) = exp2(d2 * (-log2e/alpha)) — one mul + v_exp_f32.
    const float nia = -1.4426950408889634f * __builtin_amdgcn_rcpf(alpha);

    const int b = tid / HW;
    const int p = tid % HW;

    const float* lab_b = x_lab + (size_t)b * N * 3 * HW + p;
    const float* ab_b  = x_ab  + (size_t)b * N * 2 * HW + p;
    float*       out_b = out   + (size_t)b * N * 2 * HW + p;

    // Stage this pixel's 40 input floats in registers (static indexing).
    float lab[N][3];
    float ab[N][2];
#pragma unroll
    for (int j = 0; j < N; ++j) {
#pragma unroll
        for (int c = 0; c < 3; ++c)
            lab[j][c] = lab_b[(size_t)(j * 3 + c) * HW];
#pragma unroll
        for (int c = 0; c < 2; ++c)
            ab[j][c] = ab_b[(size_t)(j * 2 + c) * HW];
    }

#pragma unroll
    for (int i = 0; i < N; ++i) {
        float s = 0.f, a0 = 0.f, a1 = 0.f;
#pragma unroll
        for (int j = 0; j < N; ++j) {
            float d0 = lab[j][0] - lab[i][0];
            float d1 = lab[j][1] - lab[i][1];
            float d2 = lab[j][2] - lab[i][2];
            float dd = d0 * d0 + d1 * d1 + d2 * d2;
            float w  = __builtin_amdgcn_exp2f(dd * nia);
            s  += w;
            a0 += w * ab[j][0];
            a1 += w * ab[j][1];
        }
        float r = __builtin_amdgcn_rcpf(s);
        out_b[(size_t)(i * 2 + 0) * HW] = a0 * r;
        out_b[(size_t)(i * 2 + 1) * HW] = a1 * r;
    }
}

extern "C" void kernel_launch(void* const* d_in, const int* in_sizes, int n_in,
                              void* d_out, int out_size, void* d_ws, size_t ws_size,
                              hipStream_t stream) {
    const float* x_lab = (const float*)d_in[0];
    const float* x_ab  = (const float*)d_in[1];
    const int*   alpha = (const int*)d_in[2];
    float* out = (float*)d_out;

    const int total_threads = B * HW;          // 589824 (one pixel each)
    const int block = 256;
    const int grid = total_threads / block;    // 2304 blocks -> 9216 waves
    wavg_color_temporal_kernel<<<grid, block, 0, stream>>>(x_lab, x_ab, alpha, out);
}